// Round 7
// baseline (465.513 us; speedup 1.0000x reference)
//
#include <hip/hip_runtime.h>
#include <stdint.h>

#define NIMG 32
#define H 1024
#define W 1024
#define BH 73
#define BW 73
#define NCHUNK (NIMG * BH)        // 2336 chunks; chunk = n*73 + by
#define TOTAL (NIMG * BH * BW)    // 170528
#define BS 14                     // block stride
#define KW 16                     // pool window
#define NT 256

#define ST_AGG  0x40000000u       // aggregate published
#define ST_PRE  0x80000000u       // inclusive prefix published
#define ST_RDY  (ST_AGG | ST_PRE)
#define ST_VAL  0x3FFFFFFFu

// Single-dispatch pool + decoupled-lookback scan + scatter.
// vs round 5 (congestion collapse at 390 us): s_sleep backoff in every spin
// poll. Ticket-ordered chunks guarantee forward progress: all predecessors in
// ticket order are already executing and publish their aggregate before any
// wait of their own.
__global__ __launch_bounds__(NT) void fused_kernel(const float* __restrict__ mask,
                                                   unsigned* __restrict__ status,   // [NCHUNK], zeroed
                                                   unsigned* __restrict__ ticket,   // zeroed
                                                   int* __restrict__ out_idx) {
    int t = threadIdx.x;
    int lane = t & 63;
    int wave = t >> 6;
    __shared__ float colmax[W];
    __shared__ int sred[4];
    __shared__ int schunk;
    __shared__ int sexcl;

    if (t == 0) schunk = (int)atomicAdd(ticket, 1u);
    __syncthreads();
    int chunk = schunk;
    int n  = chunk / BH;
    int by = chunk - n * BH;
    const float* img = mask + (size_t)n * (H * W);

    // ---------------- pool: 16x16 window max, stride 14, pad 1 ----------------
    int y0 = by * BS - 1;
    float4 v[8];
#pragma unroll
    for (int r = 0; r < 8; ++r) {              // rows 0..7, clamped (dup row 0
        int y = y0 + r;                        //  is a no-op under max)
        y = (y < 0) ? 0 : y;
        v[r] = ((const float4*)(img + (size_t)y * W))[t];
    }
    float4 acc = v[0];
#pragma unroll
    for (int r = 1; r < 8; ++r) {
        acc.x = fmaxf(acc.x, v[r].x);
        acc.y = fmaxf(acc.y, v[r].y);
        acc.z = fmaxf(acc.z, v[r].z);
        acc.w = fmaxf(acc.w, v[r].w);
    }
#pragma unroll
    for (int r = 0; r < 8; ++r) {              // rows 8..15 (never clamped)
        v[r] = ((const float4*)(img + (size_t)(y0 + 8 + r) * W))[t];
    }
#pragma unroll
    for (int r = 0; r < 8; ++r) {
        acc.x = fmaxf(acc.x, v[r].x);
        acc.y = fmaxf(acc.y, v[r].y);
        acc.z = fmaxf(acc.z, v[r].z);
        acc.w = fmaxf(acc.w, v[r].w);
    }
    ((float4*)colmax)[t] = acc;
    __syncthreads();

    int flag = 0;
    if (t < BW) {
        int x0 = t * BS - 1;
        float m = colmax[x0 < 0 ? 0 : x0];
#pragma unroll
        for (int c = 1; c < KW; ++c) m = fmaxf(m, colmax[x0 + c]);  // in [0,1022]
        flag = (m > 0.5f) ? 1 : 0;
    }
    unsigned long long b = __ballot(flag);
    if (lane == 0) sred[wave] = __popcll(b);
    __syncthreads();
    int count = sred[0] + sred[1] + sred[2] + sred[3];

    // ---------------- publish + decoupled lookback (with backoff) ----------------
    if (t == 0) {
        unsigned pub = ((chunk == 0) ? ST_PRE : ST_AGG) | (unsigned)count;
        __hip_atomic_store(&status[chunk], pub, __ATOMIC_RELEASE, __HIP_MEMORY_SCOPE_AGENT);
        if (chunk == 0) sexcl = 0;
    }
    if (wave == 0 && chunk > 0) {
        int excl = 0;                          // meaningful on lane 0 only
        int j = chunk - 1;
        for (;;) {
            int idx = j - lane;                // lane 0 = closest predecessor
            unsigned s;
            for (;;) {                         // spin until whole window ready
                s = (idx >= 0)
                    ? __hip_atomic_load(&status[idx], __ATOMIC_ACQUIRE, __HIP_MEMORY_SCOPE_AGENT)
                    : ST_PRE;                  // virtual prefix=0 before chunk 0
                unsigned long long rdy = __ballot((s & ST_RDY) != 0);
                if (rdy == ~0ull) break;
                __builtin_amdgcn_s_sleep(4);   // ~256 cyc backoff: kills the
            }                                  //  round-5 coherence flood
            unsigned long long pre = __ballot((s & ST_PRE) != 0);
            int val = (int)(s & ST_VAL);
            int contrib;
            if (pre) {
                int lp = __ffsll((unsigned long long)pre) - 1;  // closest prefix
                contrib = (lane <= lp) ? val : 0;  // its prefix + nearer aggregates
            } else {
                contrib = val;                 // all aggregates, keep walking
            }
            contrib += __shfl_down(contrib, 32);
            contrib += __shfl_down(contrib, 16);
            contrib += __shfl_down(contrib, 8);
            contrib += __shfl_down(contrib, 4);
            contrib += __shfl_down(contrib, 2);
            contrib += __shfl_down(contrib, 1);
            excl += contrib;                   // valid on lane 0
            if (pre) break;
            j -= 64;
        }
        if (lane == 0) {
            __hip_atomic_store(&status[chunk], ST_PRE | (unsigned)(excl + count),
                               __ATOMIC_RELEASE, __HIP_MEMORY_SCOPE_AGENT);
            sexcl = excl;
        }
    }
    __syncthreads();
    int excl = sexcl;                          // global exclusive prefix of chunk

    // ---------------- scatter: active triples + tail fill ----------------
    if (t < BW) {
        int wavebase = (wave >= 1) ? sred[0] : 0;   // t<73 spans waves 0,1 only
        int apre = __popcll(b & ((1ull << lane) - 1ull)) + wavebase;
        if (flag) {
            int o = (excl + apre) * 3;
            out_idx[o]     = n;
            out_idx[o + 1] = by;
            out_idx[o + 2] = t;
        } else {
            // fill rows are identical -> any disjoint tail tiling works
            int inactive_before = chunk * BW - excl;
            int ipre = t - apre;               // inactive rank within chunk
            int p = TOTAL - inactive_before - (BW - count) + ipre;
            int o = p * 3;
            out_idx[o]     = NIMG;
            out_idx[o + 1] = BH;
            out_idx[o + 2] = BW;
        }
    }
    if (chunk == NCHUNK - 1 && t == 0)
        out_idx[(size_t)TOTAL * 3] = excl + count;  // grand total, for free
}

extern "C" void kernel_launch(void* const* d_in, const int* in_sizes, int n_in,
                              void* d_out, int out_size, void* d_ws, size_t ws_size,
                              hipStream_t stream) {
    const float* mask = (const float*)d_in[0];
    int* out = (int*)d_out;

    unsigned* status = (unsigned*)d_ws;        // [NCHUNK]
    unsigned* ticket = status + NCHUNK;        // [1]

    // ws is poisoned 0xAA (fake ready bits) — zero status + ticket first.
    hipMemsetAsync(d_ws, 0, (NCHUNK + 1) * sizeof(unsigned), stream);
    fused_kernel<<<NCHUNK, NT, 0, stream>>>(mask, status, ticket, out);
}

// Round 8
// 194.750 us; speedup vs baseline: 2.3903x; 2.3903x over previous
//
#include <hip/hip_runtime.h>
#include <stdint.h>

#define NIMG 32
#define H 1024
#define W 1024
#define BH 73
#define BW 73
#define NCHUNK (NIMG * BH)        // 2336 chunks; chunk = n*73 + by
#define TOTAL (NIMG * BH * BW)    // 170528
#define BS 14                     // block stride
#define KW 16                     // pool window
#define NGRP ((NCHUNK + 63) / 64) // 37 groups of 64 chunks

__device__ __forceinline__ int wave_reduce(int x) {
    x += __shfl_down(x, 32);
    x += __shfl_down(x, 16);
    x += __shfl_down(x, 8);
    x += __shfl_down(x, 4);
    x += __shfl_down(x, 2);
    x += __shfl_down(x, 1);
    return x;                      // valid on lane 0
}

// ---------------------------------------------------------------------------
// Kernel A: per-(n,by) strip max-pool (two batches of 8 independent float4
// row loads -> MLP=8). Writes flags (1 B/block), per-chunk count, and
// atomicAdd's the count into its 64-chunk group sum (order-independent ->
// deterministic). No prefill: kernel B writes the tail fill directly.
// ---------------------------------------------------------------------------
__global__ __launch_bounds__(256) void pool_kernel(const float* __restrict__ mask,
                                                   uint8_t* __restrict__ flags,
                                                   int* __restrict__ counts,
                                                   int* __restrict__ gsum) {
    int chunk = blockIdx.x;
    int n  = chunk / BH;
    int by = chunk - n * BH;
    const float* img = mask + (size_t)n * (H * W);
    int t = threadIdx.x;
    int lane = t & 63;
    int wave = t >> 6;
    __shared__ float colmax[W];
    __shared__ int sred[4];

    int y0 = by * BS - 1;
    float4 v[8];
#pragma unroll
    for (int r = 0; r < 8; ++r) {              // rows 0..7, clamped (dup row 0
        int y = y0 + r;                        //  is a no-op under max)
        y = (y < 0) ? 0 : y;
        v[r] = ((const float4*)(img + (size_t)y * W))[t];
    }
    float4 acc = v[0];
#pragma unroll
    for (int r = 1; r < 8; ++r) {
        acc.x = fmaxf(acc.x, v[r].x);
        acc.y = fmaxf(acc.y, v[r].y);
        acc.z = fmaxf(acc.z, v[r].z);
        acc.w = fmaxf(acc.w, v[r].w);
    }
#pragma unroll
    for (int r = 0; r < 8; ++r) {              // rows 8..15 (never clamped)
        v[r] = ((const float4*)(img + (size_t)(y0 + 8 + r) * W))[t];
    }
#pragma unroll
    for (int r = 0; r < 8; ++r) {
        acc.x = fmaxf(acc.x, v[r].x);
        acc.y = fmaxf(acc.y, v[r].y);
        acc.z = fmaxf(acc.z, v[r].z);
        acc.w = fmaxf(acc.w, v[r].w);
    }
    ((float4*)colmax)[t] = acc;
    __syncthreads();

    int flag = 0;
    if (t < BW) {
        int x0 = t * BS - 1;
        float m = colmax[x0 < 0 ? 0 : x0];
#pragma unroll
        for (int c = 1; c < KW; ++c) m = fmaxf(m, colmax[x0 + c]);  // [0,1022]
        flag = (m > 0.5f) ? 1 : 0;
        flags[chunk * BW + t] = (uint8_t)flag;
    }
    unsigned long long b = __ballot(flag);
    if (lane == 0) sred[wave] = __popcll(b);
    __syncthreads();
    if (t == 0) {
        int count = sred[0] + sred[1] + sred[2] + sred[3];
        counts[chunk] = count;
        atomicAdd(&gsum[chunk >> 6], count);   // order-independent: exact
    }
}

// ---------------------------------------------------------------------------
// Kernel B: exclusive prefix from group sums (<=36 loads) + within-group
// counts (<=63 loads), all lane-parallel in one 128-thread reduce; ballot
// rank; scatter active triples; tail fill for inactive slots (fill rows are
// identical, so any disjoint tail tiling is correct — verified r5-r7).
// Block 0 writes the grand total from the 37 group sums.
// ---------------------------------------------------------------------------
__global__ __launch_bounds__(128) void scatter_kernel(const uint8_t* __restrict__ flags,
                                                      const int* __restrict__ counts,
                                                      const int* __restrict__ gsum,
                                                      int* __restrict__ out_idx) {
    int chunk = blockIdx.x;
    int n  = chunk / BH;
    int by = chunk - n * BH;
    int t = threadIdx.x;              // 0..127
    int lane = t & 63;
    int wave = t >> 6;
    __shared__ int sred[2];
    __shared__ int bcnt[2];

    int flag = (t < BW) ? (int)flags[chunk * BW + t] : 0;

    // exclusive prefix of chunk: full groups (wave 0) + within-group (wave 1)
    int g  = chunk >> 6;
    int cb = g << 6;
    int local = 0;
    if (t < g) local += gsum[t];                       // g <= 36 < 64
    if (t >= 64 && (t - 64) < (chunk - cb)) local += counts[cb + (t - 64)];
    local = wave_reduce(local);
    if (lane == 0) sred[wave] = local;
    unsigned long long b = __ballot(flag);
    if (lane == 0) bcnt[wave] = __popcll(b);
    __syncthreads();
    int excl  = sred[0] + sred[1];
    int count = bcnt[0] + bcnt[1];

    if (t < BW) {
        int apre = __popcll(b & ((1ull << lane) - 1ull)) + (wave == 1 ? bcnt[0] : 0);
        if (flag) {
            int o = (excl + apre) * 3;
            out_idx[o]     = n;
            out_idx[o + 1] = by;
            out_idx[o + 2] = t;
        } else {
            int inactive_before = chunk * BW - excl;   // inactive in chunks < c
            int ipre = t - apre;                       // inactive rank in chunk
            int p = TOTAL - inactive_before - (BW - count) + ipre;
            int o = p * 3;
            out_idx[o]     = NIMG;
            out_idx[o + 1] = BH;
            out_idx[o + 2] = BW;
        }
    }

    if (chunk == 0 && wave == 0) {            // grand total from 37 group sums
        int tot = (lane < NGRP) ? gsum[lane] : 0;
        tot = wave_reduce(tot);
        if (lane == 0) out_idx[(size_t)TOTAL * 3] = tot;
    }
}

extern "C" void kernel_launch(void* const* d_in, const int* in_sizes, int n_in,
                              void* d_out, int out_size, void* d_ws, size_t ws_size,
                              hipStream_t stream) {
    const float* mask = (const float*)d_in[0];
    int* out = (int*)d_out;

    int* counts = (int*)d_ws;                           // [NCHUNK]
    int* gsum   = counts + NCHUNK;                      // [NGRP]
    uint8_t* flags = (uint8_t*)(gsum + NGRP);           // [NCHUNK*BW]

    // gsum is atomically accumulated — must start at 0 (ws is poisoned 0xAA)
    hipMemsetAsync(gsum, 0, NGRP * sizeof(int), stream);
    pool_kernel<<<NCHUNK, 256, 0, stream>>>(mask, flags, counts, gsum);
    scatter_kernel<<<NCHUNK, 128, 0, stream>>>(flags, counts, gsum, out);
}

// Round 9
// 193.554 us; speedup vs baseline: 2.4051x; 1.0062x over previous
//
#include <hip/hip_runtime.h>
#include <stdint.h>

#define NIMG 32
#define H 1024
#define W 1024
#define BH 73
#define BW 73
#define NCHUNK (NIMG * BH)        // 2336 chunks; chunk = n*73 + by
#define TOTAL (NIMG * BH * BW)    // 170528
#define BS 14                     // block stride
#define KW 16                     // pool window

__device__ __forceinline__ int wave_reduce(int x) {
    x += __shfl_down(x, 32);
    x += __shfl_down(x, 16);
    x += __shfl_down(x, 8);
    x += __shfl_down(x, 4);
    x += __shfl_down(x, 2);
    x += __shfl_down(x, 1);
    return x;                      // valid on lane 0
}

// ---------------------------------------------------------------------------
// Kernel A: per-(n,by) strip max-pool. Two batches of 8 independent float4
// row loads (MLP=8; row clamp instead of trip-count keeps them independent —
// dup row 0 is a no-op under max). Writes flags (1 B/block) + per-chunk
// count. No prefill (B tail-fills), no atomics, no memset needed.
// ---------------------------------------------------------------------------
__global__ __launch_bounds__(256) void pool_kernel(const float* __restrict__ mask,
                                                   uint8_t* __restrict__ flags,
                                                   int* __restrict__ counts) {
    int chunk = blockIdx.x;
    int n  = chunk / BH;
    int by = chunk - n * BH;
    const float* img = mask + (size_t)n * (H * W);
    int t = threadIdx.x;
    int lane = t & 63;
    int wave = t >> 6;
    __shared__ float colmax[W];
    __shared__ int sred[4];

    int y0 = by * BS - 1;
    float4 v[8];
#pragma unroll
    for (int r = 0; r < 8; ++r) {              // rows 0..7, clamped
        int y = y0 + r;
        y = (y < 0) ? 0 : y;
        v[r] = ((const float4*)(img + (size_t)y * W))[t];
    }
    float4 acc = v[0];
#pragma unroll
    for (int r = 1; r < 8; ++r) {
        acc.x = fmaxf(acc.x, v[r].x);
        acc.y = fmaxf(acc.y, v[r].y);
        acc.z = fmaxf(acc.z, v[r].z);
        acc.w = fmaxf(acc.w, v[r].w);
    }
#pragma unroll
    for (int r = 0; r < 8; ++r) {              // rows 8..15 (never clamped)
        v[r] = ((const float4*)(img + (size_t)(y0 + 8 + r) * W))[t];
    }
#pragma unroll
    for (int r = 0; r < 8; ++r) {
        acc.x = fmaxf(acc.x, v[r].x);
        acc.y = fmaxf(acc.y, v[r].y);
        acc.z = fmaxf(acc.z, v[r].z);
        acc.w = fmaxf(acc.w, v[r].w);
    }
    ((float4*)colmax)[t] = acc;
    __syncthreads();

    int flag = 0;
    if (t < BW) {
        int x0 = t * BS - 1;
        float m = colmax[x0 < 0 ? 0 : x0];
#pragma unroll
        for (int c = 1; c < KW; ++c) m = fmaxf(m, colmax[x0 + c]);  // [0,1022]
        flag = (m > 0.5f) ? 1 : 0;
        flags[chunk * BW + t] = (uint8_t)flag;
    }
    unsigned long long b = __ballot(flag);
    if (lane == 0) sred[wave] = __popcll(b);
    __syncthreads();
    if (t == 0) counts[chunk] = sred[0] + sred[1] + sred[2] + sred[3];
}

// ---------------------------------------------------------------------------
// Kernel B: exclusive prefix via block-parallel loop over the 9 KB L2-hot
// counts array (<=18 iters/thread); ballot rank; scatter active triples;
// tail fill for inactive slots (fill rows identical -> any disjoint tail
// tiling is correct, verified r5-r8). Last chunk writes the grand total
// (excl + count, free).
// ---------------------------------------------------------------------------
__global__ __launch_bounds__(128) void scatter_kernel(const uint8_t* __restrict__ flags,
                                                      const int* __restrict__ counts,
                                                      int* __restrict__ out_idx) {
    int chunk = blockIdx.x;
    int n  = chunk / BH;
    int by = chunk - n * BH;
    int t = threadIdx.x;              // 0..127
    int lane = t & 63;
    int wave = t >> 6;
    __shared__ int sred[2];
    __shared__ int bcnt[2];

    int flag = (t < BW) ? (int)flags[chunk * BW + t] : 0;

    // exclusive prefix of this chunk
    int local = 0;
    for (int i = t; i < chunk; i += 128) local += counts[i];
    local = wave_reduce(local);
    if (lane == 0) sred[wave] = local;
    unsigned long long b = __ballot(flag);
    if (lane == 0) bcnt[wave] = __popcll(b);
    __syncthreads();
    int excl  = sred[0] + sred[1];
    int count = bcnt[0] + bcnt[1];    // flags only exist for t<73

    if (t < BW) {
        int apre = __popcll(b & ((1ull << lane) - 1ull)) + (wave == 1 ? bcnt[0] : 0);
        if (flag) {
            int o = (excl + apre) * 3;
            out_idx[o]     = n;
            out_idx[o + 1] = by;
            out_idx[o + 2] = t;
        } else {
            int inactive_before = chunk * BW - excl;   // inactive in chunks < c
            int ipre = t - apre;                       // inactive rank in chunk
            int p = TOTAL - inactive_before - (BW - count) + ipre;
            int o = p * 3;
            out_idx[o]     = NIMG;
            out_idx[o + 1] = BH;
            out_idx[o + 2] = BW;
        }
    }

    if (chunk == NCHUNK - 1 && t == 0)
        out_idx[(size_t)TOTAL * 3] = excl + count;     // grand total
}

extern "C" void kernel_launch(void* const* d_in, const int* in_sizes, int n_in,
                              void* d_out, int out_size, void* d_ws, size_t ws_size,
                              hipStream_t stream) {
    const float* mask = (const float*)d_in[0];
    int* out = (int*)d_out;

    int* counts = (int*)d_ws;                           // [NCHUNK]
    uint8_t* flags = (uint8_t*)(counts + NCHUNK);       // [NCHUNK*BW]

    pool_kernel<<<NCHUNK, 256, 0, stream>>>(mask, flags, counts);
    scatter_kernel<<<NCHUNK, 128, 0, stream>>>(flags, counts, out);
}